// Round 4
// baseline (116.335 us; speedup 1.0000x reference)
//
#include <hip/hip_runtime.h>

#define Bc 8
#define Tc 8
#define Cc 32
#define Hc 16
#define Wc 28
#define NHc 4
#define DKc 8
#define HWc (Hc*Wc)                  // 448
#define INV_SCALE 0.35355339059327373f
#define LOG2E 1.4426950408889634f
#define LN2f 0.6931471805599453f
#define LN_EPSc 1e-5f

#if __has_builtin(__builtin_amdgcn_exp2f)
#define EXP2f(x) __builtin_amdgcn_exp2f(x)
#else
#define EXP2f(x) exp2f(x)
#endif

typedef _Float16 half8  __attribute__((ext_vector_type(8)));
typedef _Float16 half2v __attribute__((ext_vector_type(2)));
typedef float    f2     __attribute__((ext_vector_type(2)));

union H8 { half8 v; half2v h2[4]; };

// Global layouts:
//   Qh : [bh][t][hw]      half8  (LN'd, pre-scaled by INV_SCALE*log2e, fp16)
//   Kh : [bh][s][hw]      half8  (fp16)
//   Vh : [bh][s][hw]      half8  (fp16 — R2 proved precision-safe; halves
//                                 K2's V LDS traffic, the LDS-BW floor)
//   Tp : [bh][s][t][hw]   half8  (fp16 partials; raw-score weights, *ln2)
//   LM : [bh][s][t][hw]   float2 (l = corrected sum exp, m = max, log2-dom)

// ---------------------------------------------------------------------------
// Kernel 1: QKV projection + fused LayerNorm of q.
// grid = 256, 448 threads.  blk = head*64 + bt (blk and blk+64 are congruent
// mod 8 -> same XCD, so the 4 blocks sharing one bt slice L2-share first/x).
// ---------------------------------------------------------------------------
__global__ __launch_bounds__(448) void qkv_ln_kernel(
    const float* __restrict__ first, const float* __restrict__ x,
    const float* __restrict__ Wq, const float* __restrict__ Wk,
    const float* __restrict__ Wv,
    const float* __restrict__ gamma, const float* __restrict__ beta,
    half8* __restrict__ Qh, half8* __restrict__ Kh, half8* __restrict__ Vh)
{
    int blk  = blockIdx.x;           // head*64 + bt
    int head = blk >> 6;
    int bt   = blk & 63;             // b*T + t
    int t    = bt % Tc;
    int b    = bt / Tc;
    int tid  = threadIdx.x;          // h*W + w

    const float* fp = first + (size_t)bt * Cc * HWc + tid;
    const float* xp = x     + (size_t)bt * Cc * HWc + tid;
    float fv[Cc], xv[Cc];
#pragma unroll
    for (int c = 0; c < Cc; ++c) { fv[c] = fp[c*HWc]; xv[c] = xp[c*HWc]; }

    float qv[DKc], kv[DKc], vv[DKc];
#pragma unroll
    for (int dk = 0; dk < DKc; ++dk) {
        int o = head*DKc + dk;       // lane-uniform -> scalar loads of weights
        float aq = 0.f, ak = 0.f, av = 0.f;
#pragma unroll
        for (int c = 0; c < Cc; ++c) {
            aq = fmaf(Wq[o*Cc+c], fv[c], aq);
            ak = fmaf(Wk[o*Cc+c], xv[c], ak);
            av = fmaf(Wv[o*Cc+c], xv[c], av);
        }
        qv[dk] = aq; kv[dk] = ak; vv[dk] = av;
    }

    int bh = b*NHc + head;
    half8 kh, vh;
#pragma unroll
    for (int dk = 0; dk < DKc; ++dk) {
        kh[dk] = (_Float16)kv[dk];
        vh[dk] = (_Float16)vv[dk];
    }
    Kh[((size_t)bh*Tc + t)*HWc + tid] = kh;
    Vh[((size_t)bh*Tc + t)*HWc + tid] = vh;

    // LayerNorm over (DK,H,W) = 3584 values for this (b,t,head)
    float s1 = 0.f, s2 = 0.f;
#pragma unroll
    for (int dk = 0; dk < DKc; ++dk) { s1 += qv[dk]; s2 += qv[dk]*qv[dk]; }
#pragma unroll
    for (int off = 32; off >= 1; off >>= 1) {
        s1 += __shfl_down(s1, off, 64);
        s2 += __shfl_down(s2, off, 64);
    }
    __shared__ float r1[8], r2[8];
    int wid = tid >> 6, lane = tid & 63;
    if (lane == 0) { r1[wid] = s1; r2[wid] = s2; }
    __syncthreads();
    float S1 = 0.f, S2 = 0.f;
#pragma unroll
    for (int wv2 = 0; wv2 < 7; ++wv2) { S1 += r1[wv2]; S2 += r2[wv2]; }
    const float invN = 1.f / (float)(DKc * HWc);
    float mu   = S1 * invN;
    float var  = S2 * invN - mu*mu;
    float rstd = rsqrtf(var + LN_EPSc);

    // pre-scale by INV_SCALE*log2e: scores come out in log2 domain so the
    // softmax exp is a single v_exp_f32 (no per-tap multiply).
    const float QSCALE = INV_SCALE * LOG2E;
    half8 qh;
#pragma unroll
    for (int dk = 0; dk < DKc; ++dk) {
        float gg = gamma[dk*HWc + tid];
        float bb = beta [dk*HWc + tid];
        qh[dk] = (_Float16)(((qv[dk] - mu) * rstd * gg + bb) * QSCALE);
    }
    Qh[((size_t)bh*Tc + t)*HWc + tid] = qh;
}

// ---------------------------------------------------------------------------
// Kernel 2: attention.  t_batch = 4, grid = 512 single-item blocks.
// Stride-256 complementary-head pairing: blk and blk+256 co-resident on one
// CU; blk<256 -> heads {0,1}, blk>=256 -> heads {3,2} (heavy+light mix).
//
// R4: R3 structure + fp16 V in LDS (K2 LDS traffic 48B -> 32B per tap; the
// LDS-BW floor was the binding constraint: 147 ds_read_b128/thread ~ 10us
// across 256 CUs vs ~6us VALU) + s_setprio(1) around the tap loop (T5:
// independent blocks on one CU, the attn-proven regime).  fp32 accumulate
// kept; V converted once per tap (8 v_cvt amortized over 4 j).
// ---------------------------------------------------------------------------
template<int DIL>
__device__ __forceinline__ void attn_body(
    int bh, int s, int t0, int tid,
    const half8* __restrict__ Qh, const half8* __restrict__ Kh,
    const half8* __restrict__ Vh,
    half8* __restrict__ Tpart, float2* __restrict__ LMpart,
    half8* sK, half8* sV)
{
    int w = tid % Wc;
    int h = tid / Wc;

    sK[tid] = Kh[((size_t)bh*Tc + s)*HWc + tid];
    sV[tid] = Vh[((size_t)bh*Tc + s)*HWc + tid];
    if (tid == 0) {
        half8 z = {};
        sK[HWc] = z;
        sV[HWc] = z;
    }

    H8 q[4];
#pragma unroll
    for (int j = 0; j < 4; ++j)
        q[j].v = Qh[((size_t)bh*Tc + (t0+j))*HWc + tid];

    // executed taps = (valid dy rows) x 7; invalid dx among them hit the zero
    // slot and each adds exactly exp2(0)=1.0 to l.
    int nvy = 0, nvx = 0;
#pragma unroll
    for (int d = -3; d <= 3; ++d) {
        nvy += ((unsigned)(h + d*DIL) < (unsigned)Hc);
        nvx += ((unsigned)(w + d*DIL) < (unsigned)Wc);
    }
    float corr = (float)(nvy * (7 - nvx));

    f2 a[4][4];
    float l[4], m[4];
#pragma unroll
    for (int j = 0; j < 4; ++j) {
#pragma unroll
        for (int u = 0; u < 4; ++u) a[j][u] = (f2){0.f, 0.f};
        l[j] = 0.f; m[j] = -1e30f;
    }

    __syncthreads();

    __builtin_amdgcn_s_setprio(1);
#pragma unroll
    for (int dy = -3; dy <= 3; ++dy) {
        int hy = h + dy*DIL;
        if ((unsigned)hy >= (unsigned)Hc) continue;   // exec-mask row skip
        int rowbase = hy*Wc;
#pragma unroll
        for (int dx = -3; dx <= 3; ++dx) {
            int wx = w + dx*DIL;                      // dx*DIL = inline const
            bool cv = (unsigned)wx < (unsigned)Wc;
            int idx = cv ? (rowbase + wx) : HWc;      // zero slot if invalid
            H8 k;  k.v  = sK[idx];
            H8 vh; vh.v = sV[idx];
            // fp16 V -> fp32 once per tap (amortized over 4 j)
            f2 v0 = {(float)vh.v[0], (float)vh.v[1]};
            f2 v1 = {(float)vh.v[2], (float)vh.v[3]};
            f2 v2 = {(float)vh.v[4], (float)vh.v[5]};
            f2 v3 = {(float)vh.v[6], (float)vh.v[7]};
#pragma unroll
            for (int j = 0; j < 4; ++j) {
                float sc = __builtin_amdgcn_fdot2(q[j].h2[0], k.h2[0],
                           __builtin_amdgcn_fdot2(q[j].h2[1], k.h2[1],
                           __builtin_amdgcn_fdot2(q[j].h2[2], k.h2[2],
                           __builtin_amdgcn_fdot2(q[j].h2[3], k.h2[3],
                                                  0.f, false), false), false), false);
                m[j] = fmaxf(m[j], sc);               // log2-domain max
                l[j] += EXP2f(sc);                    // single v_exp_f32
                f2 sc2 = {sc, sc};
                // invalid lanes: k=0 -> sc=0 -> zero contribution; v=0 too
                a[j][0] = __builtin_elementwise_fma(sc2, v0, a[j][0]);
                a[j][1] = __builtin_elementwise_fma(sc2, v1, a[j][1]);
                a[j][2] = __builtin_elementwise_fma(sc2, v2, a[j][2]);
                a[j][3] = __builtin_elementwise_fma(sc2, v3, a[j][3]);
            }
        }
    }
    __builtin_amdgcn_s_setprio(0);

    half8*  tp  = Tpart  + (size_t)(bh*Tc + s)*Tc*HWc + tid;
    float2* lmp = LMpart + (size_t)(bh*Tc + s)*Tc*HWc + tid;
#pragma unroll
    for (int j = 0; j < 4; ++j) {
        // V weights must be raw (scale-divided) scores: undo the log2e
        // prescale once here instead of per-tap.
        half8 hv;
#pragma unroll
        for (int u = 0; u < 4; ++u) {
            hv[2*u]   = (_Float16)(a[j][u][0] * LN2f);
            hv[2*u+1] = (_Float16)(a[j][u][1] * LN2f);
        }
        tp [(t0+j)*HWc] = hv;
        lmp[(t0+j)*HWc] = make_float2(l[j] - corr, m[j]);
    }
}

__global__ __launch_bounds__(448, 4) void attn_kernel(
    const half8* __restrict__ Qh, const half8* __restrict__ Kh,
    const half8* __restrict__ Vh,
    half8* __restrict__ Tpart, float2* __restrict__ LMpart)
{
    int blk = blockIdx.x;
    int p   = blk >> 8;              // pairing half
    int i   = blk & 255;
    int b   = i >> 5;
    int ha  = (i >> 4) & 1;
    int s   = (i >> 1) & 7;
    int th  = i & 1;

    int head = p ? (3 - ha) : ha;
    int bh   = b*NHc + head;
    int t0   = th*4;
    int tid  = threadIdx.x;

    __shared__ half8 sK[HWc+1];                       // 7184 B (+ zero slot)
    __shared__ half8 sV[HWc+1];                       // 7184 B

    if      (head == 0) attn_body<1>(bh, s, t0, tid, Qh, Kh, Vh, Tpart, LMpart, sK, sV);
    else if (head == 1) attn_body<3>(bh, s, t0, tid, Qh, Kh, Vh, Tpart, LMpart, sK, sV);
    else if (head == 2) attn_body<5>(bh, s, t0, tid, Qh, Kh, Vh, Tpart, LMpart, sK, sV);
    else                attn_body<7>(bh, s, t0, tid, Qh, Kh, Vh, Tpart, LMpart, sK, sV);
}

// ---------------------------------------------------------------------------
// Kernel 3: fused combine + output projection.
// grid = 256 blocks (blk = og*64 + bt; the 4 og blocks sharing one bt are 64
// apart -> same XCD, so the 4x replicated Tpart/LM reads are L2-served).
// ---------------------------------------------------------------------------
__global__ __launch_bounds__(448) void outproj_kernel(
    const half8* __restrict__ Tpart, const float2* __restrict__ LMpart,
    const float* __restrict__ Wo, float* __restrict__ out)
{
    int blk = blockIdx.x;            // og*64 + bt
    int og  = blk >> 6;
    int bt  = blk & 63;
    int b   = bt >> 3, t = bt & 7;
    int tid = threadIdx.x;           // h*W + w

    float mv[Cc];
    float MS = 0.f;
#pragma unroll
    for (int head = 0; head < NHc; ++head) {
        int bh = b*NHc + head;
        float acc[DKc];
#pragma unroll
        for (int j = 0; j < DKc; ++j) acc[j] = 0.f;
        float lsum = 0.f, mmax = -1e30f;
#pragma unroll
        for (int s = 0; s < Tc; ++s) {
            half8 u = Tpart[(size_t)((bh*Tc + s)*Tc + t)*HWc + tid];
#pragma unroll
            for (int j = 0; j < DKc; ++j) acc[j] += (float)u[j];
            float2 lm = LMpart[(size_t)((bh*Tc + s)*Tc + t)*HWc + tid];
            lsum += lm.x; mmax = fmaxf(mmax, lm.y);
        }
#pragma unroll
        for (int j = 0; j < DKc; ++j) mv[head*DKc + j] = acc[j];
        // m is in log2 domain -> exp2
        MS = fmaxf(MS, EXP2f(mmax) / lsum);
    }
#pragma unroll
    for (int i = 0; i < 8; ++i) {
        int o = og*8 + i;
        float a = 0.f;
#pragma unroll
        for (int c = 0; c < Cc; ++c) a = fmaf(Wo[o*Cc+c], mv[c], a);
        out[((size_t)bt*Cc + o)*HWc + tid] = a * MS;
    }
}

// ---------------------------------------------------------------------------
extern "C" void kernel_launch(void* const* d_in, const int* in_sizes, int n_in,
                              void* d_out, int out_size, void* d_ws, size_t ws_size,
                              hipStream_t stream) {
    const float* first = (const float*)d_in[0];
    const float* x     = (const float*)d_in[1];
    const float* Wq    = (const float*)d_in[2];
    const float* Wk    = (const float*)d_in[3];
    const float* Wv    = (const float*)d_in[4];
    const float* Wo    = (const float*)d_in[5];
    const float* g     = (const float*)d_in[6];
    const float* bta   = (const float*)d_in[7];
    float* out = (float*)d_out;

    float* ws = (float*)d_ws;
    const size_t N5 = (size_t)Bc*NHc*Tc*HWc*DKc;    // 917504 elements
    half8*  Qh  = (half8*)ws;                        // N5 halves = N5/2 floats
    half8*  Kh  = (half8*)(ws + N5/2);               // N5 halves
    half8*  Vh  = (half8*)(ws + N5);                 // N5 halves
    half8*  Tp  = (half8*)(ws + 3*N5/2);             // 8*N5 halves = 4*N5 floats
    float2* LMp = (float2*)(ws + 3*N5/2 + 4*N5);     // 2*N5 floats
    // total: 7.5*N5 floats ~= 27.5 MB

    qkv_ln_kernel <<<Bc*Tc*NHc, 448, 0, stream>>>(first, x, Wq, Wk, Wv, g, bta, Qh, Kh, Vh);
    attn_kernel   <<<512,       448, 0, stream>>>(Qh, Kh, Vh, Tp, LMp);
    outproj_kernel<<<256,       448, 0, stream>>>(Tp, LMp, Wo, out);
}

// Round 5
// 111.105 us; speedup vs baseline: 1.0471x; 1.0471x over previous
//
#include <hip/hip_runtime.h>

#define Bc 8
#define Tc 8
#define Cc 32
#define Hc 16
#define Wc 28
#define NHc 4
#define DKc 8
#define HWc (Hc*Wc)                  // 448
#define INV_SCALE 0.35355339059327373f
#define LOG2E 1.4426950408889634f
#define LN2f 0.6931471805599453f
#define LN_EPSc 1e-5f

#if __has_builtin(__builtin_amdgcn_exp2f)
#define EXP2f(x) __builtin_amdgcn_exp2f(x)
#else
#define EXP2f(x) exp2f(x)
#endif

typedef _Float16 half8  __attribute__((ext_vector_type(8)));
typedef _Float16 half2v __attribute__((ext_vector_type(2)));
typedef float    f2     __attribute__((ext_vector_type(2)));

union H8 { half8 v; half2v h2[4]; };
union F4 { float4 f4; f2 p[2]; };

// Global layouts:
//   Qh : [bh][t][hw]      half8  (LN'd, pre-scaled by INV_SCALE*log2e, fp16)
//   Kh : [bh][s][hw]      half8  (fp16)
//   V  : [bh][s][hw][dk]  float  (fp32 — R3-proven best; fp16 LDS V regressed R4)
//   Tp : [bh][s][t][hw]   half8  (fp16 partials; raw-score weights, *ln2)
//   LM : [bh][s][t][hw]   float2 (l = corrected sum exp, m = max, log2-dom)

// ---------------------------------------------------------------------------
// Kernel 1: QKV projection + fused LayerNorm of q.  (R3 verbatim)
// ---------------------------------------------------------------------------
__global__ __launch_bounds__(448) void qkv_ln_kernel(
    const float* __restrict__ first, const float* __restrict__ x,
    const float* __restrict__ Wq, const float* __restrict__ Wk,
    const float* __restrict__ Wv,
    const float* __restrict__ gamma, const float* __restrict__ beta,
    half8* __restrict__ Qh, half8* __restrict__ Kh, float* __restrict__ V)
{
    int blk  = blockIdx.x;           // head*64 + bt
    int head = blk >> 6;
    int bt   = blk & 63;             // b*T + t
    int t    = bt % Tc;
    int b    = bt / Tc;
    int tid  = threadIdx.x;          // h*W + w

    const float* fp = first + (size_t)bt * Cc * HWc + tid;
    const float* xp = x     + (size_t)bt * Cc * HWc + tid;
    float fv[Cc], xv[Cc];
#pragma unroll
    for (int c = 0; c < Cc; ++c) { fv[c] = fp[c*HWc]; xv[c] = xp[c*HWc]; }

    float qv[DKc], kv[DKc], vv[DKc];
#pragma unroll
    for (int dk = 0; dk < DKc; ++dk) {
        int o = head*DKc + dk;       // lane-uniform -> scalar loads of weights
        float aq = 0.f, ak = 0.f, av = 0.f;
#pragma unroll
        for (int c = 0; c < Cc; ++c) {
            aq = fmaf(Wq[o*Cc+c], fv[c], aq);
            ak = fmaf(Wk[o*Cc+c], xv[c], ak);
            av = fmaf(Wv[o*Cc+c], xv[c], av);
        }
        qv[dk] = aq; kv[dk] = ak; vv[dk] = av;
    }

    int bh = b*NHc + head;
    half8 kh;
#pragma unroll
    for (int dk = 0; dk < DKc; ++dk) kh[dk] = (_Float16)kv[dk];
    Kh[((size_t)bh*Tc + t)*HWc + tid] = kh;

    float* vp = V + (((size_t)bh*Tc + t)*HWc + tid)*DKc;
    *(float4*)(vp)   = make_float4(vv[0],vv[1],vv[2],vv[3]);
    *(float4*)(vp+4) = make_float4(vv[4],vv[5],vv[6],vv[7]);

    // LayerNorm over (DK,H,W) = 3584 values for this (b,t,head)
    float s1 = 0.f, s2 = 0.f;
#pragma unroll
    for (int dk = 0; dk < DKc; ++dk) { s1 += qv[dk]; s2 += qv[dk]*qv[dk]; }
#pragma unroll
    for (int off = 32; off >= 1; off >>= 1) {
        s1 += __shfl_down(s1, off, 64);
        s2 += __shfl_down(s2, off, 64);
    }
    __shared__ float r1[8], r2[8];
    int wid = tid >> 6, lane = tid & 63;
    if (lane == 0) { r1[wid] = s1; r2[wid] = s2; }
    __syncthreads();
    float S1 = 0.f, S2 = 0.f;
#pragma unroll
    for (int wv2 = 0; wv2 < 7; ++wv2) { S1 += r1[wv2]; S2 += r2[wv2]; }
    const float invN = 1.f / (float)(DKc * HWc);
    float mu   = S1 * invN;
    float var  = S2 * invN - mu*mu;
    float rstd = rsqrtf(var + LN_EPSc);

    // pre-scale by INV_SCALE*log2e: scores come out in log2 domain so the
    // softmax exp is a single v_exp_f32 (no per-tap multiply).
    const float QSCALE = INV_SCALE * LOG2E;
    half8 qh;
#pragma unroll
    for (int dk = 0; dk < DKc; ++dk) {
        float gg = gamma[dk*HWc + tid];
        float bb = beta [dk*HWc + tid];
        qh[dk] = (_Float16)(((qv[dk] - mu) * rstd * gg + bb) * QSCALE);
    }
    Qh[((size_t)bh*Tc + t)*HWc + tid] = qh;
}

// ---------------------------------------------------------------------------
// Kernel 2: attention.  (R3 verbatim — proven best at 113.0 µs)
// t_batch = 4, grid = 512; stride-256 complementary-head pairing.
// Zero-slot masking + log2-domain scores + template<DIL> + packed fp32
// V-accumulate.  No setprio (regressed in R4), fp32 V in LDS (fp16 regressed).
// ---------------------------------------------------------------------------
template<int DIL>
__device__ __forceinline__ void attn_body(
    int bh, int s, int t0, int tid,
    const half8* __restrict__ Qh, const half8* __restrict__ Kh,
    const float* __restrict__ V,
    half8* __restrict__ Tpart, float2* __restrict__ LMpart,
    half8* sK, float4* sV0, float4* sV1)
{
    int w = tid % Wc;
    int h = tid / Wc;

    sK[tid] = Kh[((size_t)bh*Tc + s)*HWc + tid];
    const float* vp = V + ((size_t)bh*Tc + s)*HWc*DKc;
    sV0[tid] = *(const float4*)(vp + tid*DKc);
    sV1[tid] = *(const float4*)(vp + tid*DKc + 4);
    if (tid == 0) {
        half8 z = {};
        sK[HWc]  = z;
        sV0[HWc] = make_float4(0.f,0.f,0.f,0.f);
        sV1[HWc] = make_float4(0.f,0.f,0.f,0.f);
    }

    H8 q[4];
#pragma unroll
    for (int j = 0; j < 4; ++j)
        q[j].v = Qh[((size_t)bh*Tc + (t0+j))*HWc + tid];

    // executed taps = (valid dy rows) x 7; invalid dx among them hit the zero
    // slot and each adds exactly exp2(0)=1.0 to l.
    int nvy = 0, nvx = 0;
#pragma unroll
    for (int d = -3; d <= 3; ++d) {
        nvy += ((unsigned)(h + d*DIL) < (unsigned)Hc);
        nvx += ((unsigned)(w + d*DIL) < (unsigned)Wc);
    }
    float corr = (float)(nvy * (7 - nvx));

    f2 a[4][4];
    float l[4], m[4];
#pragma unroll
    for (int j = 0; j < 4; ++j) {
#pragma unroll
        for (int u = 0; u < 4; ++u) a[j][u] = (f2){0.f, 0.f};
        l[j] = 0.f; m[j] = -1e30f;
    }

    __syncthreads();

#pragma unroll
    for (int dy = -3; dy <= 3; ++dy) {
        int hy = h + dy*DIL;
        if ((unsigned)hy >= (unsigned)Hc) continue;   // exec-mask row skip
        int rowbase = hy*Wc;
#pragma unroll
        for (int dx = -3; dx <= 3; ++dx) {
            int wx = w + dx*DIL;                      // dx*DIL = inline const
            bool cv = (unsigned)wx < (unsigned)Wc;
            int idx = cv ? (rowbase + wx) : HWc;      // zero slot if invalid
            H8 k; k.v = sK[idx];
            F4 v0, v1; v0.f4 = sV0[idx]; v1.f4 = sV1[idx];
#pragma unroll
            for (int j = 0; j < 4; ++j) {
                float sc = __builtin_amdgcn_fdot2(q[j].h2[0], k.h2[0],
                           __builtin_amdgcn_fdot2(q[j].h2[1], k.h2[1],
                           __builtin_amdgcn_fdot2(q[j].h2[2], k.h2[2],
                           __builtin_amdgcn_fdot2(q[j].h2[3], k.h2[3],
                                                  0.f, false), false), false), false);
                m[j] = fmaxf(m[j], sc);               // log2-domain max
                l[j] += EXP2f(sc);                    // single v_exp_f32
                f2 sc2 = {sc, sc};
                // invalid lanes: k=0 -> sc=0 -> zero contribution; v=0 too
                a[j][0] = __builtin_elementwise_fma(sc2, v0.p[0], a[j][0]);
                a[j][1] = __builtin_elementwise_fma(sc2, v0.p[1], a[j][1]);
                a[j][2] = __builtin_elementwise_fma(sc2, v1.p[0], a[j][2]);
                a[j][3] = __builtin_elementwise_fma(sc2, v1.p[1], a[j][3]);
            }
        }
    }

    half8*  tp  = Tpart  + (size_t)(bh*Tc + s)*Tc*HWc + tid;
    float2* lmp = LMpart + (size_t)(bh*Tc + s)*Tc*HWc + tid;
#pragma unroll
    for (int j = 0; j < 4; ++j) {
        // V weights must be raw (scale-divided) scores: undo the log2e
        // prescale once here instead of per-tap.
        half8 hv;
#pragma unroll
        for (int u = 0; u < 4; ++u) {
            hv[2*u]   = (_Float16)(a[j][u][0] * LN2f);
            hv[2*u+1] = (_Float16)(a[j][u][1] * LN2f);
        }
        tp [(t0+j)*HWc] = hv;
        lmp[(t0+j)*HWc] = make_float2(l[j] - corr, m[j]);
    }
}

__global__ __launch_bounds__(448, 4) void attn_kernel(
    const half8* __restrict__ Qh, const half8* __restrict__ Kh,
    const float* __restrict__ V,
    half8* __restrict__ Tpart, float2* __restrict__ LMpart)
{
    int blk = blockIdx.x;
    int p   = blk >> 8;              // pairing half
    int i   = blk & 255;
    int b   = i >> 5;
    int ha  = (i >> 4) & 1;
    int s   = (i >> 1) & 7;
    int th  = i & 1;

    int head = p ? (3 - ha) : ha;
    int bh   = b*NHc + head;
    int t0   = th*4;
    int tid  = threadIdx.x;

    __shared__ half8  sK [HWc+1];                     // 7184 B (+ zero slot)
    __shared__ float4 sV0[HWc+1], sV1[HWc+1];         // 14368 B

    if      (head == 0) attn_body<1>(bh, s, t0, tid, Qh, Kh, V, Tpart, LMpart, sK, sV0, sV1);
    else if (head == 1) attn_body<3>(bh, s, t0, tid, Qh, Kh, V, Tpart, LMpart, sK, sV0, sV1);
    else if (head == 2) attn_body<5>(bh, s, t0, tid, Qh, Kh, V, Tpart, LMpart, sK, sV0, sV1);
    else                attn_body<7>(bh, s, t0, tid, Qh, Kh, V, Tpart, LMpart, sK, sV0, sV1);
}

// ---------------------------------------------------------------------------
// Kernel 3: fused combine + output projection — two-phase, redundancy-free.
// R5: grid = 256 blocks = hq(4) x bt(64); each block owns one hw-quarter and
// reads its Tpart/LM slices EXACTLY ONCE (old og-split read them 4x: 88 MB
// -> 22 MB of global reads).  Phase 1: threads = (head x 112 hw) reduce over
// s, stage mv/l/m in LDS (row stride 41 floats; 41 mod 32 = 9, odd -> reads
// across u hit distinct banks).  Phase 2: threads = (oq x 112 hw) combine
// softmax-max scale + 32x32 projection with Wo staged in LDS (reads are
// <=2-way broadcast across the oq groups = free).  Out stores: fixed o,
// consecutive hw -> coalesced 112-float runs, same as before.
// ---------------------------------------------------------------------------
#define MVS 41                        // LDS row stride (floats), odd mod 32

__global__ __launch_bounds__(448) void outproj_kernel(
    const half8* __restrict__ Tpart, const float2* __restrict__ LMpart,
    const float* __restrict__ Wo, float* __restrict__ out)
{
    int blk = blockIdx.x;            // hq*64 + bt
    int hq  = blk >> 6;
    int bt  = blk & 63;
    int b   = bt >> 3, t = bt & 7;
    int tid = threadIdx.x;

    __shared__ float smv[112*MVS];   // [u][0..31]=mv, [32+h]=l, [36+h]=m
    __shared__ float swo[Cc*Cc];     // 32x32 Wo

    // stage Wo (1024 floats, coalesced)
    for (int i = tid; i < Cc*Cc; i += 448) swo[i] = Wo[i];

    // ---- phase 1: (head, u) reduce over s --------------------------------
    {
        int head = tid / 112;        // 0..3
        int u    = tid - head*112;   // 0..111
        int hw   = hq*112 + u;
        int bh   = b*NHc + head;

        float acc[DKc];
#pragma unroll
        for (int j = 0; j < DKc; ++j) acc[j] = 0.f;
        float lsum = 0.f, mmax = -1e30f;
#pragma unroll
        for (int s = 0; s < Tc; ++s) {
            half8 uvec = Tpart[(size_t)((bh*Tc + s)*Tc + t)*HWc + hw];
#pragma unroll
            for (int j = 0; j < DKc; ++j) acc[j] += (float)uvec[j];
            float2 lm = LMpart[(size_t)((bh*Tc + s)*Tc + t)*HWc + hw];
            lsum += lm.x; mmax = fmaxf(mmax, lm.y);
        }
        float* row = smv + u*MVS;
#pragma unroll
        for (int j = 0; j < DKc; ++j) row[head*DKc + j] = acc[j];
        row[32 + head] = lsum;
        row[36 + head] = mmax;
    }
    __syncthreads();

    // ---- phase 2: (oq, u) softmax-max scale + projection -----------------
    {
        int oq = tid / 112;          // 0..3
        int u  = tid - oq*112;       // 0..111
        const float* row = smv + u*MVS;

        float MS = 0.f;
#pragma unroll
        for (int hh = 0; hh < NHc; ++hh)
            MS = fmaxf(MS, EXP2f(row[36 + hh]) / row[32 + hh]);

        float mv[Cc];
#pragma unroll
        for (int c = 0; c < Cc; ++c) mv[c] = row[c];

#pragma unroll
        for (int i = 0; i < 8; ++i) {
            int o = oq*8 + i;
            float a = 0.f;
#pragma unroll
            for (int c = 0; c < Cc; ++c) a = fmaf(swo[o*Cc + c], mv[c], a);
            out[((size_t)bt*Cc + o)*HWc + hq*112 + u] = a * MS;
        }
    }
}

// ---------------------------------------------------------------------------
extern "C" void kernel_launch(void* const* d_in, const int* in_sizes, int n_in,
                              void* d_out, int out_size, void* d_ws, size_t ws_size,
                              hipStream_t stream) {
    const float* first = (const float*)d_in[0];
    const float* x     = (const float*)d_in[1];
    const float* Wq    = (const float*)d_in[2];
    const float* Wk    = (const float*)d_in[3];
    const float* Wv    = (const float*)d_in[4];
    const float* Wo    = (const float*)d_in[5];
    const float* g     = (const float*)d_in[6];
    const float* bta   = (const float*)d_in[7];
    float* out = (float*)d_out;

    float* ws = (float*)d_ws;
    const size_t N5 = (size_t)Bc*NHc*Tc*HWc*DKc;    // 917504 elements
    half8*  Qh  = (half8*)ws;                        // N5 halves = N5/2 floats
    half8*  Kh  = (half8*)(ws + N5/2);               // N5 halves
    float*  V   = ws + N5;                           // N5 floats (fp32)
    half8*  Tp  = (half8*)(ws + 2*N5);               // 917504 half8 = 4*N5 floats
    float2* LMp = (float2*)(ws + 6*N5);              // 917504 float2 = 2*N5 floats
    // total: 8*N5 floats ~= 29.4 MB

    qkv_ln_kernel <<<Bc*Tc*NHc, 448, 0, stream>>>(first, x, Wq, Wk, Wv, g, bta, Qh, Kh, V);
    attn_kernel   <<<512,       448, 0, stream>>>(Qh, Kh, V, Tp, LMp);
    outproj_kernel<<<256,       448, 0, stream>>>(Tp, LMp, Wo, out);
}

// Round 6
// 109.572 us; speedup vs baseline: 1.0617x; 1.0140x over previous
//
#include <hip/hip_runtime.h>

#define Bc 8
#define Tc 8
#define Cc 32
#define Hc 16
#define Wc 28
#define NHc 4
#define DKc 8
#define HWc (Hc*Wc)                  // 448
#define INV_SCALE 0.35355339059327373f
#define LOG2E 1.4426950408889634f
#define LN2f 0.6931471805599453f
#define LN_EPSc 1e-5f

#if __has_builtin(__builtin_amdgcn_exp2f)
#define EXP2f(x) __builtin_amdgcn_exp2f(x)
#else
#define EXP2f(x) exp2f(x)
#endif

typedef _Float16 half8  __attribute__((ext_vector_type(8)));
typedef _Float16 half2v __attribute__((ext_vector_type(2)));
typedef float    f2     __attribute__((ext_vector_type(2)));

union H8 { half8 v; half2v h2[4]; };
union F4 { float4 f4; f2 p[2]; };

// Global layouts:
//   Qh : [bh][t][hw]      half8  (LN'd, pre-scaled by INV_SCALE*log2e, fp16)
//   Kh : [bh][s][hw]      half8  (fp16)
//   Vh : [bh][s][hw]      half8  (fp16 in GLOBAL only; converted to fp32
//                                 once per thread during K2 LDS staging —
//                                 inner loop identical to R5's fp32 path.
//                                 R4's regression was per-tap cvt + setprio.)
//   Tp : [bh][s][t][hw]   half8  (fp16 partials; raw-score weights, *ln2)
//   LM : [bh][s][t][hw]   float2 (l = corrected sum exp, m = max, log2-dom)

// ---------------------------------------------------------------------------
// Kernel 1: QKV projection + fused LayerNorm of q.
// grid = 256, 448 threads.  blk = head*64 + bt (blk and blk+64 congruent
// mod 8 -> same XCD, so the 4 blocks sharing one bt slice L2-share first/x).
// ---------------------------------------------------------------------------
__global__ __launch_bounds__(448) void qkv_ln_kernel(
    const float* __restrict__ first, const float* __restrict__ x,
    const float* __restrict__ Wq, const float* __restrict__ Wk,
    const float* __restrict__ Wv,
    const float* __restrict__ gamma, const float* __restrict__ beta,
    half8* __restrict__ Qh, half8* __restrict__ Kh, half8* __restrict__ Vh)
{
    int blk  = blockIdx.x;           // head*64 + bt
    int head = blk >> 6;
    int bt   = blk & 63;             // b*T + t
    int t    = bt % Tc;
    int b    = bt / Tc;
    int tid  = threadIdx.x;          // h*W + w

    const float* fp = first + (size_t)bt * Cc * HWc + tid;
    const float* xp = x     + (size_t)bt * Cc * HWc + tid;
    float fv[Cc], xv[Cc];
#pragma unroll
    for (int c = 0; c < Cc; ++c) { fv[c] = fp[c*HWc]; xv[c] = xp[c*HWc]; }

    float qv[DKc], kv[DKc], vv[DKc];
#pragma unroll
    for (int dk = 0; dk < DKc; ++dk) {
        int o = head*DKc + dk;       // lane-uniform -> scalar loads of weights
        float aq = 0.f, ak = 0.f, av = 0.f;
#pragma unroll
        for (int c = 0; c < Cc; ++c) {
            aq = fmaf(Wq[o*Cc+c], fv[c], aq);
            ak = fmaf(Wk[o*Cc+c], xv[c], ak);
            av = fmaf(Wv[o*Cc+c], xv[c], av);
        }
        qv[dk] = aq; kv[dk] = ak; vv[dk] = av;
    }

    int bh = b*NHc + head;
    half8 kh, vh;
#pragma unroll
    for (int dk = 0; dk < DKc; ++dk) {
        kh[dk] = (_Float16)kv[dk];
        vh[dk] = (_Float16)vv[dk];
    }
    Kh[((size_t)bh*Tc + t)*HWc + tid] = kh;
    Vh[((size_t)bh*Tc + t)*HWc + tid] = vh;

    // LayerNorm over (DK,H,W) = 3584 values for this (b,t,head)
    float s1 = 0.f, s2 = 0.f;
#pragma unroll
    for (int dk = 0; dk < DKc; ++dk) { s1 += qv[dk]; s2 += qv[dk]*qv[dk]; }
#pragma unroll
    for (int off = 32; off >= 1; off >>= 1) {
        s1 += __shfl_down(s1, off, 64);
        s2 += __shfl_down(s2, off, 64);
    }
    __shared__ float r1[8], r2[8];
    int wid = tid >> 6, lane = tid & 63;
    if (lane == 0) { r1[wid] = s1; r2[wid] = s2; }
    __syncthreads();
    float S1 = 0.f, S2 = 0.f;
#pragma unroll
    for (int wv2 = 0; wv2 < 7; ++wv2) { S1 += r1[wv2]; S2 += r2[wv2]; }
    const float invN = 1.f / (float)(DKc * HWc);
    float mu   = S1 * invN;
    float var  = S2 * invN - mu*mu;
    float rstd = rsqrtf(var + LN_EPSc);

    // pre-scale by INV_SCALE*log2e: scores come out in log2 domain so the
    // softmax exp is a single v_exp_f32 (no per-tap multiply).
    const float QSCALE = INV_SCALE * LOG2E;
    half8 qh;
#pragma unroll
    for (int dk = 0; dk < DKc; ++dk) {
        float gg = gamma[dk*HWc + tid];
        float bb = beta [dk*HWc + tid];
        qh[dk] = (_Float16)(((qv[dk] - mu) * rstd * gg + bb) * QSCALE);
    }
    Qh[((size_t)bh*Tc + t)*HWc + tid] = qh;
}

// ---------------------------------------------------------------------------
// Kernel 2: attention.  t_batch = 4, grid = 512; stride-256 complementary-
// head pairing.  Inner loop identical to R5 (proven best): zero-slot
// masking + log2-domain scores + template<DIL> + packed fp32 V-accumulate.
// Only the V staging changed: global V is fp16, converted to fp32 float4
// LDS once per thread (8 cvt total, amortized over all 196 tap-units).
// ---------------------------------------------------------------------------
template<int DIL>
__device__ __forceinline__ void attn_body(
    int bh, int s, int t0, int tid,
    const half8* __restrict__ Qh, const half8* __restrict__ Kh,
    const half8* __restrict__ Vh,
    half8* __restrict__ Tpart, float2* __restrict__ LMpart,
    half8* sK, float4* sV0, float4* sV1)
{
    int w = tid % Wc;
    int h = tid / Wc;

    sK[tid] = Kh[((size_t)bh*Tc + s)*HWc + tid];
    H8 vg; vg.v = Vh[((size_t)bh*Tc + s)*HWc + tid];
    sV0[tid] = make_float4((float)vg.v[0], (float)vg.v[1],
                           (float)vg.v[2], (float)vg.v[3]);
    sV1[tid] = make_float4((float)vg.v[4], (float)vg.v[5],
                           (float)vg.v[6], (float)vg.v[7]);
    if (tid == 0) {
        half8 z = {};
        sK[HWc]  = z;
        sV0[HWc] = make_float4(0.f,0.f,0.f,0.f);
        sV1[HWc] = make_float4(0.f,0.f,0.f,0.f);
    }

    H8 q[4];
#pragma unroll
    for (int j = 0; j < 4; ++j)
        q[j].v = Qh[((size_t)bh*Tc + (t0+j))*HWc + tid];

    // executed taps = (valid dy rows) x 7; invalid dx among them hit the zero
    // slot and each adds exactly exp2(0)=1.0 to l.
    int nvy = 0, nvx = 0;
#pragma unroll
    for (int d = -3; d <= 3; ++d) {
        nvy += ((unsigned)(h + d*DIL) < (unsigned)Hc);
        nvx += ((unsigned)(w + d*DIL) < (unsigned)Wc);
    }
    float corr = (float)(nvy * (7 - nvx));

    f2 a[4][4];
    float l[4], m[4];
#pragma unroll
    for (int j = 0; j < 4; ++j) {
#pragma unroll
        for (int u = 0; u < 4; ++u) a[j][u] = (f2){0.f, 0.f};
        l[j] = 0.f; m[j] = -1e30f;
    }

    __syncthreads();

#pragma unroll
    for (int dy = -3; dy <= 3; ++dy) {
        int hy = h + dy*DIL;
        if ((unsigned)hy >= (unsigned)Hc) continue;   // exec-mask row skip
        int rowbase = hy*Wc;
#pragma unroll
        for (int dx = -3; dx <= 3; ++dx) {
            int wx = w + dx*DIL;                      // dx*DIL = inline const
            bool cv = (unsigned)wx < (unsigned)Wc;
            int idx = cv ? (rowbase + wx) : HWc;      // zero slot if invalid
            H8 k; k.v = sK[idx];
            F4 v0, v1; v0.f4 = sV0[idx]; v1.f4 = sV1[idx];
#pragma unroll
            for (int j = 0; j < 4; ++j) {
                float sc = __builtin_amdgcn_fdot2(q[j].h2[0], k.h2[0],
                           __builtin_amdgcn_fdot2(q[j].h2[1], k.h2[1],
                           __builtin_amdgcn_fdot2(q[j].h2[2], k.h2[2],
                           __builtin_amdgcn_fdot2(q[j].h2[3], k.h2[3],
                                                  0.f, false), false), false), false);
                m[j] = fmaxf(m[j], sc);               // log2-domain max
                l[j] += EXP2f(sc);                    // single v_exp_f32
                f2 sc2 = {sc, sc};
                // invalid lanes: k=0 -> sc=0 -> zero contribution; v=0 too
                a[j][0] = __builtin_elementwise_fma(sc2, v0.p[0], a[j][0]);
                a[j][1] = __builtin_elementwise_fma(sc2, v0.p[1], a[j][1]);
                a[j][2] = __builtin_elementwise_fma(sc2, v1.p[0], a[j][2]);
                a[j][3] = __builtin_elementwise_fma(sc2, v1.p[1], a[j][3]);
            }
        }
    }

    half8*  tp  = Tpart  + (size_t)(bh*Tc + s)*Tc*HWc + tid;
    float2* lmp = LMpart + (size_t)(bh*Tc + s)*Tc*HWc + tid;
#pragma unroll
    for (int j = 0; j < 4; ++j) {
        // V weights must be raw (scale-divided) scores: undo the log2e
        // prescale once here instead of per-tap.
        half8 hv;
#pragma unroll
        for (int u = 0; u < 4; ++u) {
            hv[2*u]   = (_Float16)(a[j][u][0] * LN2f);
            hv[2*u+1] = (_Float16)(a[j][u][1] * LN2f);
        }
        tp [(t0+j)*HWc] = hv;
        lmp[(t0+j)*HWc] = make_float2(l[j] - corr, m[j]);
    }
}

__global__ __launch_bounds__(448, 4) void attn_kernel(
    const half8* __restrict__ Qh, const half8* __restrict__ Kh,
    const half8* __restrict__ Vh,
    half8* __restrict__ Tpart, float2* __restrict__ LMpart)
{
    int blk = blockIdx.x;
    int p   = blk >> 8;              // pairing half
    int i   = blk & 255;
    int b   = i >> 5;
    int ha  = (i >> 4) & 1;
    int s   = (i >> 1) & 7;
    int th  = i & 1;

    int head = p ? (3 - ha) : ha;
    int bh   = b*NHc + head;
    int t0   = th*4;
    int tid  = threadIdx.x;

    __shared__ half8  sK [HWc+1];                     // 7184 B (+ zero slot)
    __shared__ float4 sV0[HWc+1], sV1[HWc+1];         // 14368 B

    if      (head == 0) attn_body<1>(bh, s, t0, tid, Qh, Kh, Vh, Tpart, LMpart, sK, sV0, sV1);
    else if (head == 1) attn_body<3>(bh, s, t0, tid, Qh, Kh, Vh, Tpart, LMpart, sK, sV0, sV1);
    else if (head == 2) attn_body<5>(bh, s, t0, tid, Qh, Kh, Vh, Tpart, LMpart, sK, sV0, sV1);
    else                attn_body<7>(bh, s, t0, tid, Qh, Kh, Vh, Tpart, LMpart, sK, sV0, sV1);
}

// ---------------------------------------------------------------------------
// Kernel 3: fused combine + output projection — two-phase, redundancy-free.
// (R5 verbatim: each block owns one hw-quarter, reads Tpart/LM exactly once.)
// ---------------------------------------------------------------------------
#define MVS 41                        // LDS row stride (floats), odd mod 32

__global__ __launch_bounds__(448) void outproj_kernel(
    const half8* __restrict__ Tpart, const float2* __restrict__ LMpart,
    const float* __restrict__ Wo, float* __restrict__ out)
{
    int blk = blockIdx.x;            // hq*64 + bt
    int hq  = blk >> 6;
    int bt  = blk & 63;
    int b   = bt >> 3, t = bt & 7;
    int tid = threadIdx.x;

    __shared__ float smv[112*MVS];   // [u][0..31]=mv, [32+h]=l, [36+h]=m
    __shared__ float swo[Cc*Cc];     // 32x32 Wo

    // stage Wo (1024 floats, coalesced)
    for (int i = tid; i < Cc*Cc; i += 448) swo[i] = Wo[i];

    // ---- phase 1: (head, u) reduce over s --------------------------------
    {
        int head = tid / 112;        // 0..3
        int u    = tid - head*112;   // 0..111
        int hw   = hq*112 + u;
        int bh   = b*NHc + head;

        float acc[DKc];
#pragma unroll
        for (int j = 0; j < DKc; ++j) acc[j] = 0.f;
        float lsum = 0.f, mmax = -1e30f;
#pragma unroll
        for (int s = 0; s < Tc; ++s) {
            half8 uvec = Tpart[(size_t)((bh*Tc + s)*Tc + t)*HWc + hw];
#pragma unroll
            for (int j = 0; j < DKc; ++j) acc[j] += (float)uvec[j];
            float2 lm = LMpart[(size_t)((bh*Tc + s)*Tc + t)*HWc + hw];
            lsum += lm.x; mmax = fmaxf(mmax, lm.y);
        }
        float* row = smv + u*MVS;
#pragma unroll
        for (int j = 0; j < DKc; ++j) row[head*DKc + j] = acc[j];
        row[32 + head] = lsum;
        row[36 + head] = mmax;
    }
    __syncthreads();

    // ---- phase 2: (oq, u) softmax-max scale + projection -----------------
    {
        int oq = tid / 112;          // 0..3
        int u  = tid - oq*112;       // 0..111
        const float* row = smv + u*MVS;

        float MS = 0.f;
#pragma unroll
        for (int hh = 0; hh < NHc; ++hh)
            MS = fmaxf(MS, EXP2f(row[36 + hh]) / row[32 + hh]);

        float mv[Cc];
#pragma unroll
        for (int c = 0; c < Cc; ++c) mv[c] = row[c];

#pragma unroll
        for (int i = 0; i < 8; ++i) {
            int o = oq*8 + i;
            float a = 0.f;
#pragma unroll
            for (int c = 0; c < Cc; ++c) a = fmaf(swo[o*Cc + c], mv[c], a);
            out[((size_t)bt*Cc + o)*HWc + hq*112 + u] = a * MS;
        }
    }
}

// ---------------------------------------------------------------------------
extern "C" void kernel_launch(void* const* d_in, const int* in_sizes, int n_in,
                              void* d_out, int out_size, void* d_ws, size_t ws_size,
                              hipStream_t stream) {
    const float* first = (const float*)d_in[0];
    const float* x     = (const float*)d_in[1];
    const float* Wq    = (const float*)d_in[2];
    const float* Wk    = (const float*)d_in[3];
    const float* Wv    = (const float*)d_in[4];
    const float* Wo    = (const float*)d_in[5];
    const float* g     = (const float*)d_in[6];
    const float* bta   = (const float*)d_in[7];
    float* out = (float*)d_out;

    float* ws = (float*)d_ws;
    const size_t N5 = (size_t)Bc*NHc*Tc*HWc*DKc;    // 917504 elements
    half8*  Qh  = (half8*)ws;                        // N5 halves = N5/2 floats
    half8*  Kh  = (half8*)(ws + N5/2);               // N5 halves
    half8*  Vh  = (half8*)(ws + N5);                 // N5 halves (fp16 global)
    half8*  Tp  = (half8*)(ws + 3*N5/2);             // 8*N5 halves = 4*N5 floats
    float2* LMp = (float2*)(ws + 3*N5/2 + 4*N5);     // 2*N5 floats
    // total: 7.5*N5 floats ~= 27.5 MB

    qkv_ln_kernel <<<Bc*Tc*NHc, 448, 0, stream>>>(first, x, Wq, Wk, Wv, g, bta, Qh, Kh, Vh);
    attn_kernel   <<<512,       448, 0, stream>>>(Qh, Kh, Vh, Tp, LMp);
    outproj_kernel<<<256,       448, 0, stream>>>(Tp, LMp, Wo, out);
}